// Round 1
// baseline (276.992 us; speedup 1.0000x reference)
//
#include <hip/hip_runtime.h>

// ---------------- problem constants ----------------
#define NQ        300
#define NC        80
#define NE        24000      // NQ*NC
#define CAND      1000
#define KSEL      100
#define NPAIRS    4000000
#define HB        4096       // score histogram buckets (float bits >> 18)
#define FHW       65536      // 256*256
#define NMS_THR_F 0.65f
#define MAPS_INIT 0x39E3BFFFu   // order-preserving encode of -1e4f

// order-preserving float->u32 encode (monotone: larger float => larger uint)
__device__ __forceinline__ unsigned enc_f32(float f) {
    unsigned u = __float_as_uint(f);
    return (u & 0x80000000u) ? ~u : (u | 0x80000000u);
}
__device__ __forceinline__ float dec_f32(unsigned k) {
    unsigned u = (k & 0x80000000u) ? (k ^ 0x80000000u) : ~k;
    return __uint_as_float(u);
}

// ---------------- K1: init compacted maps to encode(-1e4) ----------------
__global__ void k_init_maps(uint4* __restrict__ maps) {
    int i = blockIdx.x * 256 + threadIdx.x;      // 100*65536/4 = 1,638,400 exact
    uint4 v; v.x = v.y = v.z = v.w = MAPS_INIT;
    maps[i] = v;
}

// ---------------- K2: sigmoid scores -> top-1000 sorted candidates ----------------
// single block, 1024 threads. keys held in registers (24 per thread);
// histogram-select threshold bucket, compact to LDS, bitonic sort descending.
__global__ __launch_bounds__(1024) void k_select_sort(
    const float* __restrict__ cls,        // [300,81]
    const float* __restrict__ pboxes,     // [300,4]
    float4* __restrict__ cboxes, float* __restrict__ cscore,
    int* __restrict__ cfeat, int* __restrict__ clabel)
{
    __shared__ unsigned long long sbuf[4096];          // 32 KB, aliases hist
    unsigned* hist = (unsigned*)sbuf;                  // first 16 KB
    __shared__ int sB, sCount, sN;
    int tid = threadIdx.x;

    for (int b = tid; b < HB; b += 1024) hist[b] = 0u;
    __syncthreads();

    unsigned long long lk[24];
    #pragma unroll
    for (int k = 0; k < 24; k++) {
        int e = tid + (k << 10);
        if (e < NE) {
            int q = e / NC, c = e - q * NC;
            float x = cls[q * (NC + 1) + c];
            float s = 1.f / (1.f + expf(-x));          // scores in (0,1) -> bits monotone
            unsigned bits = __float_as_uint(s);
            lk[k] = ((unsigned long long)bits << 32) | (unsigned)(0xFFFFFFFFu - (unsigned)e);
            atomicAdd(&hist[bits >> 18], 1u);
        }
    }
    __syncthreads();

    if (tid == 0) {
        int acc = 0, B = 0;
        for (int b = HB - 1; b >= 0; b--) {            // top buckets ~empty; exits in ~50 iters
            acc += (int)hist[b];
            if (acc >= CAND) { B = b; break; }
        }
        sB = B; sCount = 0;
    }
    __syncthreads();
    unsigned B = (unsigned)sB;

    #pragma unroll
    for (int k = 0; k < 24; k++) {                     // compact keys with bucket >= B
        int e = tid + (k << 10);
        if (e < NE) {
            unsigned long long key = lk[k];
            if ((unsigned)(key >> 50) >= B) {          // key>>50 == bits>>18
                int pos = atomicAdd(&sCount, 1);
                if (pos < 4096) sbuf[pos] = key;
            }
        }
    }
    __syncthreads();
    int n = min(sCount, 4096);                         // >= 1000 by construction
    int nsort = 1024; while (nsort < n) nsort <<= 1;
    for (int i = n + tid; i < nsort; i += 1024) sbuf[i] = 0ULL;
    __syncthreads();

    for (int k = 2; k <= nsort; k <<= 1) {             // bitonic, descending
        for (int j = k >> 1; j > 0; j >>= 1) {
            for (int i = tid; i < nsort; i += 1024) {
                int ixj = i ^ j;
                if (ixj > i) {
                    unsigned long long a = sbuf[i], b = sbuf[ixj];
                    bool up = ((i & k) == 0);
                    if (up ? (a < b) : (a > b)) { sbuf[i] = b; sbuf[ixj] = a; }
                }
            }
            __syncthreads();
        }
    }

    if (tid < CAND) {
        unsigned long long key = sbuf[tid];
        unsigned bits = (unsigned)(key >> 32);
        unsigned e = 0xFFFFFFFFu - (unsigned)(key & 0xFFFFFFFFu);
        int feat = (int)e / NC, lab = (int)e - feat * NC;
        cscore[tid] = __uint_as_float(bits);
        cfeat[tid]  = feat;
        clabel[tid] = lab;
        float off = 4.f * (float)lab;                  // class-aware box offset
        float4 b;
        b.x = pboxes[feat * 4 + 0] + off; b.y = pboxes[feat * 4 + 1] + off;
        b.z = pboxes[feat * 4 + 2] + off; b.w = pboxes[feat * 4 + 3] + off;
        cboxes[tid] = b;
    }
}

// ---------------- K3: per-label greedy NMS (cross-label IoU == 0) ----------------
// one wave per label; each lane owns up to 4 candidates of its label, boxes in regs.
__global__ __launch_bounds__(64) void k_nms(
    const float4* __restrict__ cboxes, const int* __restrict__ clabel,
    int* __restrict__ keepflag)
{
    int lab = blockIdx.x, lane = threadIdx.x;
    __shared__ int list[256];
    int base = 0;
    for (int c = 0; c < CAND; c += 64) {               // ordered compaction of this label
        int i = c + lane;
        bool m = (i < CAND) && (clabel[i] == lab);
        unsigned long long bal = __ballot(m);
        int rank = __popcll(bal & ((1ULL << lane) - 1ULL));
        if (m && base + rank < 256) list[base + rank] = i;
        base += __popcll(bal);
    }
    __syncthreads();
    int n = min(base, 256);

    float4 bx[4]; float area[4];
    unsigned keepm = 0;
    #pragma unroll
    for (int s = 0; s < 4; s++) {
        int j = (s << 6) + lane;
        if (j < n) {
            bx[s] = cboxes[list[j]];
            area[s] = (bx[s].z - bx[s].x) * (bx[s].w - bx[s].y);
            keepm |= (1u << s);
        }
    }
    #pragma unroll
    for (int slot = 0; slot < 4; slot++) {             // sequential greedy over this label
        int i0 = slot << 6;
        if (i0 >= n) break;
        int iend = min(64, n - i0);
        for (int l = 0; l < iend; l++) {
            int i = i0 + l;
            unsigned km = __shfl(keepm, l);
            bool keep_i = (km >> slot) & 1u;           // uniform
            float bix = __shfl(bx[slot].x, l), biy = __shfl(bx[slot].y, l);
            float biz = __shfl(bx[slot].z, l), biw = __shfl(bx[slot].w, l);
            float ai  = __shfl(area[slot], l);
            if (keep_i) {
                #pragma unroll
                for (int s2 = 0; s2 < 4; s2++) {
                    int j = (s2 << 6) + lane;
                    if (j > i && j < n && ((keepm >> s2) & 1u)) {
                        float xx1 = fmaxf(bix, bx[s2].x), yy1 = fmaxf(biy, bx[s2].y);
                        float xx2 = fminf(biz, bx[s2].z), yy2 = fminf(biw, bx[s2].w);
                        float inter = fmaxf(xx2 - xx1, 0.f) * fmaxf(yy2 - yy1, 0.f);
                        float uni = ai + area[s2] - inter;
                        if (inter / fmaxf(uni, 1e-9f) > NMS_THR_F) keepm &= ~(1u << s2);
                    }
                }
            }
        }
    }
    #pragma unroll
    for (int s = 0; s < 4; s++) {
        int j = (s << 6) + lane;
        if (j < n) keepflag[list[j]] = (keepm >> s) & 1u;
    }
}

// ---------------- K4: pick first-100 kept, build query->slot table, dtype probe ----
__global__ __launch_bounds__(64) void k_pick(
    const float* __restrict__ cscore, const int* __restrict__ cfeat,
    const int* __restrict__ keepflag,
    float* __restrict__ sel_score, int* __restrict__ sel_slot,
    int* __restrict__ qry2slot,
    const unsigned* __restrict__ refined_raw, unsigned* __restrict__ mode_flag)
{
    int lane = threadIdx.x;
    __shared__ float ss[KSEL];
    __shared__ int   sf[KSEL];
    __shared__ int   q2s[NQ];

    // probe refined_mask layout: int32 words are strictly 0/1; packed bool bytes are not
    unsigned any = 0;
    for (int i = lane; i < 4096; i += 64) if (refined_raw[i] > 1u) any = 1;
    unsigned mode = (__ballot(any != 0) != 0ULL) ? 1u : 0u;

    int base = 0;                                      // first-100 kept, in sorted order
    for (int c = 0; c < CAND; c += 64) {
        int i = c + lane;
        bool k = (i < CAND) && (keepflag[i] != 0);
        unsigned long long bal = __ballot(k);
        int rank = __popcll(bal & ((1ULL << lane) - 1ULL));
        int pos = base + rank;
        if (k && pos < KSEL) { ss[pos] = cscore[i]; sf[pos] = cfeat[i]; }
        base += __popcll(bal);
    }
    for (int q = lane; q < NQ; q += 64) q2s[q] = -1;
    __syncthreads();
    if (lane == 0) {
        int nsel = min(base, KSEL), nslots = 0;
        for (int s = 0; s < KSEL; s++) {
            if (s < nsel) {
                int f = sf[s];
                int sl = q2s[f];
                if (sl < 0) { sl = nslots++; q2s[f] = sl; }
                sel_slot[s] = sl; sel_score[s] = ss[s];
            } else {
                sel_slot[s] = -1; sel_score[s] = 0.f;  // -inf pads -> exact 0 rows
            }
        }
        *mode_flag = mode;
    }
    __syncthreads();
    for (int q = lane; q < NQ; q += 64) qry2slot[q] = q2s[q];
}

// ---------------- K5: 4M-pair scatter-max into compacted maps ----------------
__global__ void k_scatter(
    const float* __restrict__ seg, const float2* __restrict__ xy,
    const int* __restrict__ qry, const unsigned* __restrict__ refined_raw,
    const int* __restrict__ qry2slot, const unsigned* __restrict__ mode_flag,
    unsigned* __restrict__ maps)
{
    int i = blockIdx.x * 256 + threadIdx.x;            // 15625*256 == 4,000,000 exact
    int slot = qry2slot[qry[i]];
    if (slot < 0) return;                              // query not selected
    float2 p = xy[i];
    int px = min(max((int)(p.x * 256.f), 0), 255);     // trunc == .astype(int32)
    int py = min(max((int)(p.y * 256.f), 0), 255);
    float w = seg[i];
    bool ref;
    if (*mode_flag) ref = ((const unsigned char*)refined_raw)[i] != 0;
    else            ref = refined_raw[i] != 0;
    if (ref) w *= 2.f;
    atomicMax(&maps[slot * FHW + py * 256 + px], enc_f32(w));
}

// ---------------- K6: epilogue  out = score * sigmoid(map) ----------------
__global__ void k_output(
    const unsigned* __restrict__ maps,
    const float* __restrict__ sel_score, const int* __restrict__ sel_slot,
    float* __restrict__ out)
{
    int i = blockIdx.x * 256 + threadIdx.x;            // 25600*256 == 6,553,600 exact
    int s = i >> 16;
    float sc = sel_score[s];
    int slot = sel_slot[s];
    float v = 0.f;
    if (slot >= 0) {
        float m = dec_f32(maps[slot * FHW + (i & 65535)]);
        v = sc / (1.f + expf(-m));                     // m=-1e4 -> exp=inf -> exactly 0
    }
    out[i] = v;
}

// ---------------- launch ----------------
extern "C" void kernel_launch(void* const* d_in, const int* in_sizes, int n_in,
                              void* d_out, int out_size, void* d_ws, size_t ws_size,
                              hipStream_t stream) {
    const float*    cls     = (const float*)d_in[0];
    const float*    pboxes  = (const float*)d_in[1];
    const float*    seg     = (const float*)d_in[2];
    const float2*   xy      = (const float2*)d_in[3];
    const int*      qry     = (const int*)d_in[4];
    const unsigned* refined = (const unsigned*)d_in[5];
    // d_in[6] map_ids: unused by the reference
    float* out = (float*)d_out;

    char* ws = (char*)d_ws;
    unsigned*  maps      = (unsigned*)ws;                       // 100*65536*4 = 26,214,400 B
    float4*    cboxes    = (float4*)(ws + 26214400);            // 16,000 B (16-aligned)
    float*     cscore    = (float*) (ws + 26230400);            // 4,000 B
    int*       cfeat     = (int*)   (ws + 26234400);            // 4,000 B
    int*       clabel    = (int*)   (ws + 26238400);            // 4,000 B
    int*       keepflag  = (int*)   (ws + 26242400);            // 4,000 B
    float*     sel_score = (float*) (ws + 26246400);            // 400 B
    int*       sel_slot  = (int*)   (ws + 26246800);            // 400 B
    int*       qry2slot  = (int*)   (ws + 26247200);            // 1,200 B
    unsigned*  mode_flag = (unsigned*)(ws + 26248400);          // 4 B

    k_init_maps  <<<6400, 256, 0, stream>>>((uint4*)maps);
    k_select_sort<<<1, 1024, 0, stream>>>(cls, pboxes, cboxes, cscore, cfeat, clabel);
    k_nms        <<<NC, 64, 0, stream>>>(cboxes, clabel, keepflag);
    k_pick       <<<1, 64, 0, stream>>>(cscore, cfeat, keepflag, sel_score, sel_slot,
                                        qry2slot, refined, mode_flag);
    k_scatter    <<<15625, 256, 0, stream>>>(seg, xy, qry, refined, qry2slot, mode_flag, maps);
    k_output     <<<25600, 256, 0, stream>>>(maps, sel_score, sel_slot, out);
}

// Round 3
// 248.490 us; speedup vs baseline: 1.1147x; 1.1147x over previous
//
#include <hip/hip_runtime.h>

// ---------------- problem constants ----------------
#define NQ        300
#define NC        80
#define NE        24000      // NQ*NC
#define CAND      1000
#define KSEL      100
#define NPAIRS    4000000
#define HB        4096       // score histogram buckets (float bits >> 18)
#define FHW       65536      // 256*256
#define NMS_THR_F 0.65f
#define MAPS_INIT 0x39E3BFFFu   // order-preserving encode of -1e4f

// order-preserving float->u32 encode (monotone: larger float => larger uint)
__device__ __forceinline__ unsigned enc_f32(float f) {
    unsigned u = __float_as_uint(f);
    return (u & 0x80000000u) ? ~u : (u | 0x80000000u);
}
__device__ __forceinline__ float dec_f32(unsigned k) {
    unsigned u = (k & 0x80000000u) ? (k ^ 0x80000000u) : ~k;
    return __uint_as_float(u);
}

// ---------------- K1: init compacted maps to encode(-1e4) ----------------
__global__ void k_init_maps(uint4* __restrict__ maps) {
    int i = blockIdx.x * 256 + threadIdx.x;      // 100*65536/4 = 1,638,400 exact
    uint4 v; v.x = v.y = v.z = v.w = MAPS_INIT;
    maps[i] = v;
}

// ---------------- K2: sigmoid scores -> top-1000 sorted candidates ----------------
// single block, 1024 threads. 2-level histogram select narrows to n in [1000,~1010]
// -> 1024-wide bitonic, one key per thread, j<64 phases via shfl (no barriers).
__global__ __launch_bounds__(1024) void k_select_sort(
    const float* __restrict__ cls,        // [300,81]
    const float* __restrict__ pboxes,     // [300,4]
    float4* __restrict__ cboxes, float* __restrict__ cscore,
    int* __restrict__ cfeat, int* __restrict__ clabel)
{
    __shared__ unsigned long long sbuf[4096];          // 32 KB, aliases hist
    unsigned* hist = (unsigned*)sbuf;                  // first 16 KB
    __shared__ unsigned subhist[64];
    __shared__ int sB, sT, sAbove, sCount, sN;
    int tid = threadIdx.x;

    for (int b = tid; b < HB; b += 1024) hist[b] = 0u;
    if (tid < 64) subhist[tid] = 0u;
    __syncthreads();

    unsigned long long lk[24];
    #pragma unroll
    for (int k = 0; k < 24; k++) {
        int e = tid + (k << 10);
        if (e < NE) {
            int q = e / NC, c = e - q * NC;
            float x = cls[q * (NC + 1) + c];
            float s = 1.f / (1.f + expf(-x));          // scores in (0,1) -> bits monotone
            unsigned bits = __float_as_uint(s);
            lk[k] = ((unsigned long long)bits << 32) | (unsigned)(0xFFFFFFFFu - (unsigned)e);
            atomicAdd(&hist[bits >> 18], 1u);
        }
    }
    __syncthreads();

    if (tid == 0) {
        int acc = 0, B = 0;
        for (int b = HB - 1; b >= 0; b--) {            // top buckets ~empty; ~50 iters
            acc += (int)hist[b];
            if (acc >= CAND) { B = b; break; }
        }
        sB = B; sAbove = acc - (int)hist[B]; sCount = 0;
    }
    __syncthreads();
    unsigned B = (unsigned)sB;

    #pragma unroll
    for (int k = 0; k < 24; k++) {                     // sub-histogram of bucket B
        int e = tid + (k << 10);
        if (e < NE && (unsigned)(lk[k] >> 50) == B)
            atomicAdd(&subhist[(unsigned)(lk[k] >> 44) & 63u], 1u);
    }
    __syncthreads();
    if (tid == 0) {
        int acc2 = sAbove, T = 0;
        for (int t = 63; t >= 0; t--) {
            acc2 += (int)subhist[t];
            if (acc2 >= CAND) { T = t; break; }
        }
        sT = T; sN = acc2;                             // n in [1000, 1000+subbucket]
    }
    __syncthreads();
    unsigned T = (unsigned)sT;

    #pragma unroll
    for (int k = 0; k < 24; k++) {                     // compact qualifying keys
        int e = tid + (k << 10);
        if (e < NE) {
            unsigned long long key = lk[k];
            unsigned bkt = (unsigned)(key >> 50);
            unsigned sub = (unsigned)(key >> 44) & 63u;
            if (bkt > B || (bkt == B && sub >= T)) {
                int pos = atomicAdd(&sCount, 1);
                if (pos < 4096) sbuf[pos] = key;
            }
        }
    }
    __syncthreads();
    int n = min(sN, 4096);

    if (n <= 1024) {
        // fast path: one key per thread, descending bitonic, shfl for j<64
        unsigned long long r = (tid < n) ? sbuf[tid] : 0ULL;
        for (int k = 2; k <= 1024; k <<= 1) {
            for (int j = k >> 1; j > 0; j >>= 1) {
                unsigned long long p;
                if (j >= 64) {
                    sbuf[tid] = r; __syncthreads();
                    p = sbuf[tid ^ j]; __syncthreads();
                } else {
                    p = __shfl_xor(r, j, 64);
                }
                bool d = (tid & k) != 0, lower = (tid & j) == 0;
                r = (d != lower) ? (r > p ? r : p) : (r < p ? r : p);
            }
        }
        sbuf[tid] = r;
        __syncthreads();
    } else {
        // fallback: generic LDS bitonic over next pow2
        int nsort = 2048; while (nsort < n) nsort <<= 1;
        for (int i = n + tid; i < nsort; i += 1024) sbuf[i] = 0ULL;
        __syncthreads();
        for (int k = 2; k <= nsort; k <<= 1) {
            for (int j = k >> 1; j > 0; j >>= 1) {
                for (int i = tid; i < nsort; i += 1024) {
                    int ixj = i ^ j;
                    if (ixj > i) {
                        unsigned long long a = sbuf[i], b = sbuf[ixj];
                        bool up = ((i & k) == 0);
                        if (up ? (a < b) : (a > b)) { sbuf[i] = b; sbuf[ixj] = a; }
                    }
                }
                __syncthreads();
            }
        }
    }

    if (tid < CAND) {
        unsigned long long key = sbuf[tid];
        unsigned bits = (unsigned)(key >> 32);
        unsigned e = 0xFFFFFFFFu - (unsigned)(key & 0xFFFFFFFFu);
        int feat = (int)e / NC, lab = (int)e - feat * NC;
        cscore[tid] = __uint_as_float(bits);
        cfeat[tid]  = feat;
        clabel[tid] = lab;
        float off = 4.f * (float)lab;                  // class-aware box offset
        float4 b;
        b.x = pboxes[feat * 4 + 0] + off; b.y = pboxes[feat * 4 + 1] + off;
        b.z = pboxes[feat * 4 + 2] + off; b.w = pboxes[feat * 4 + 3] + off;
        cboxes[tid] = b;
    }
}

// ---------------- K3: per-label greedy NMS (cross-label IoU == 0) ----------------
__global__ __launch_bounds__(64) void k_nms(
    const float4* __restrict__ cboxes, const int* __restrict__ clabel,
    int* __restrict__ keepflag)
{
    int lab = blockIdx.x, lane = threadIdx.x;
    __shared__ int list[256];
    int base = 0;
    for (int c = 0; c < CAND; c += 64) {               // ordered compaction of this label
        int i = c + lane;
        bool m = (i < CAND) && (clabel[i] == lab);
        unsigned long long bal = __ballot(m);
        int rank = __popcll(bal & ((1ULL << lane) - 1ULL));
        if (m && base + rank < 256) list[base + rank] = i;
        base += __popcll(bal);
    }
    __syncthreads();
    int n = min(base, 256);

    float4 bx[4]; float area[4];
    unsigned keepm = 0;
    #pragma unroll
    for (int s = 0; s < 4; s++) {
        int j = (s << 6) + lane;
        if (j < n) {
            bx[s] = cboxes[list[j]];
            area[s] = (bx[s].z - bx[s].x) * (bx[s].w - bx[s].y);
            keepm |= (1u << s);
        }
    }
    #pragma unroll
    for (int slot = 0; slot < 4; slot++) {             // sequential greedy over this label
        int i0 = slot << 6;
        if (i0 >= n) break;
        int iend = min(64, n - i0);
        for (int l = 0; l < iend; l++) {
            int i = i0 + l;
            unsigned km = __shfl(keepm, l);
            bool keep_i = (km >> slot) & 1u;           // uniform
            float bix = __shfl(bx[slot].x, l), biy = __shfl(bx[slot].y, l);
            float biz = __shfl(bx[slot].z, l), biw = __shfl(bx[slot].w, l);
            float ai  = __shfl(area[slot], l);
            if (keep_i) {
                #pragma unroll
                for (int s2 = 0; s2 < 4; s2++) {
                    int j = (s2 << 6) + lane;
                    if (j > i && j < n && ((keepm >> s2) & 1u)) {
                        float xx1 = fmaxf(bix, bx[s2].x), yy1 = fmaxf(biy, bx[s2].y);
                        float xx2 = fminf(biz, bx[s2].z), yy2 = fminf(biw, bx[s2].w);
                        float inter = fmaxf(xx2 - xx1, 0.f) * fmaxf(yy2 - yy1, 0.f);
                        float uni = ai + area[s2] - inter;
                        if (inter / fmaxf(uni, 1e-9f) > NMS_THR_F) keepm &= ~(1u << s2);
                    }
                }
            }
        }
    }
    #pragma unroll
    for (int s = 0; s < 4; s++) {
        int j = (s << 6) + lane;
        if (j < n) keepflag[list[j]] = (keepm >> s) & 1u;
    }
}

// ---------------- K4: pick first-100 kept, build query->slot table, dtype probe ----
__global__ __launch_bounds__(64) void k_pick(
    const float* __restrict__ cscore, const int* __restrict__ cfeat,
    const int* __restrict__ keepflag,
    float* __restrict__ sel_score, int* __restrict__ sel_slot,
    int* __restrict__ qry2slot,
    const unsigned* __restrict__ refined_raw, unsigned* __restrict__ mode_flag)
{
    int lane = threadIdx.x;
    __shared__ float ss[KSEL];
    __shared__ int   sf[KSEL];
    __shared__ int   q2s[NQ];

    // probe refined_mask layout: int32 words are strictly 0/1; packed bool bytes are not
    unsigned any = 0;
    for (int i = lane; i < 4096; i += 64) if (refined_raw[i] > 1u) any = 1;
    unsigned mode = (__ballot(any != 0) != 0ULL) ? 1u : 0u;

    int base = 0;                                      // first-100 kept, in sorted order
    for (int c = 0; c < CAND; c += 64) {
        int i = c + lane;
        bool k = (i < CAND) && (keepflag[i] != 0);
        unsigned long long bal = __ballot(k);
        int rank = __popcll(bal & ((1ULL << lane) - 1ULL));
        int pos = base + rank;
        if (k && pos < KSEL) { ss[pos] = cscore[i]; sf[pos] = cfeat[i]; }
        base += __popcll(bal);
    }
    for (int q = lane; q < NQ; q += 64) q2s[q] = -1;
    __syncthreads();
    if (lane == 0) {
        int nsel = min(base, KSEL), nslots = 0;
        for (int s = 0; s < KSEL; s++) {
            if (s < nsel) {
                int f = sf[s];
                int sl = q2s[f];
                if (sl < 0) { sl = nslots++; q2s[f] = sl; }
                sel_slot[s] = sl; sel_score[s] = ss[s];
            } else {
                sel_slot[s] = -1; sel_score[s] = 0.f;  // -inf pads -> exact 0 rows
            }
        }
        *mode_flag = mode;
    }
    __syncthreads();
    for (int q = lane; q < NQ; q += 64) qry2slot[q] = q2s[q];
}

// ---------------- K5: 4M-pair scatter-max, 4 pairs/thread, vectorized ----------------
__global__ __launch_bounds__(256) void k_scatter(
    const float* __restrict__ seg, const float2* __restrict__ xy,
    const int* __restrict__ qry, const unsigned* __restrict__ refined_raw,
    const int* __restrict__ qry2slot, const unsigned* __restrict__ mode_flag,
    unsigned* __restrict__ maps)
{
    int t = blockIdx.x * 256 + threadIdx.x;
    int base = t << 2;
    if (base >= NPAIRS) return;                        // NPAIRS%4==0: all-or-nothing

    int4 q4 = ((const int4*)qry)[t];
    int s0 = qry2slot[q4.x], s1 = qry2slot[q4.y];
    int s2 = qry2slot[q4.z], s3 = qry2slot[q4.w];
    if ((s0 & s1 & s2 & s3) < 0) return;               // AND: all four unselected (~24%)

    float4 sg   = ((const float4*)seg)[t];
    float4 xy01 = ((const float4*)xy)[2 * t];
    float4 xy23 = ((const float4*)xy)[2 * t + 1];
    unsigned r0, r1, r2, r3;
    if (*mode_flag) {                                  // packed bool bytes
        unsigned rb = refined_raw[t];
        r0 = rb & 255u; r1 = (rb >> 8) & 255u; r2 = (rb >> 16) & 255u; r3 = rb >> 24;
    } else {                                           // int32 words
        uint4 rr = ((const uint4*)refined_raw)[t];
        r0 = rr.x; r1 = rr.y; r2 = rr.z; r3 = rr.w;
    }

    #define DO_PAIR(S, PX, PY, W, R)                                              \
        if (S >= 0) {                                                             \
            int px = min(max((int)((PX) * 256.f), 0), 255);                       \
            int py = min(max((int)((PY) * 256.f), 0), 255);                       \
            float w = (R) ? 2.f * (W) : (W);                                      \
            atomicMax(&maps[S * FHW + py * 256 + px], enc_f32(w));                \
        }
    DO_PAIR(s0, xy01.x, xy01.y, sg.x, r0)
    DO_PAIR(s1, xy01.z, xy01.w, sg.y, r1)
    DO_PAIR(s2, xy23.x, xy23.y, sg.z, r2)
    DO_PAIR(s3, xy23.z, xy23.w, sg.w, r3)
    #undef DO_PAIR
}

// ---------------- K6: epilogue  out = score * sigmoid(map), 4 cells/thread --------
__global__ __launch_bounds__(256) void k_output(
    const uint4* __restrict__ maps4,
    const float* __restrict__ sel_score, const int* __restrict__ sel_slot,
    float4* __restrict__ out4)
{
    int i = blockIdx.x * 256 + threadIdx.x;            // 6400*256 == 1,638,400 exact
    int s = i >> 14;                                   // 16384 uint4 per segment
    float sc = sel_score[s];
    int slot = sel_slot[s];
    float4 v = {0.f, 0.f, 0.f, 0.f};
    if (slot >= 0) {
        uint4 m = maps4[slot * (FHW / 4) + (i & 16383)];
        v.x = sc / (1.f + expf(-dec_f32(m.x)));        // m=-1e4 -> exp=inf -> exactly 0
        v.y = sc / (1.f + expf(-dec_f32(m.y)));
        v.z = sc / (1.f + expf(-dec_f32(m.z)));
        v.w = sc / (1.f + expf(-dec_f32(m.w)));
    }
    out4[i] = v;
}

// ---------------- launch ----------------
extern "C" void kernel_launch(void* const* d_in, const int* in_sizes, int n_in,
                              void* d_out, int out_size, void* d_ws, size_t ws_size,
                              hipStream_t stream) {
    const float*    cls     = (const float*)d_in[0];
    const float*    pboxes  = (const float*)d_in[1];
    const float*    seg     = (const float*)d_in[2];
    const float2*   xy      = (const float2*)d_in[3];
    const int*      qry     = (const int*)d_in[4];
    const unsigned* refined = (const unsigned*)d_in[5];
    // d_in[6] map_ids: unused by the reference
    float* out = (float*)d_out;

    char* ws = (char*)d_ws;
    unsigned*  maps      = (unsigned*)ws;                       // 100*65536*4 = 26,214,400 B
    float4*    cboxes    = (float4*)(ws + 26214400);            // 16,000 B (16-aligned)
    float*     cscore    = (float*) (ws + 26230400);            // 4,000 B
    int*       cfeat     = (int*)   (ws + 26234400);            // 4,000 B
    int*       clabel    = (int*)   (ws + 26238400);            // 4,000 B
    int*       keepflag  = (int*)   (ws + 26242400);            // 4,000 B
    float*     sel_score = (float*) (ws + 26246400);            // 400 B
    int*       sel_slot  = (int*)   (ws + 26246800);            // 400 B
    int*       qry2slot  = (int*)   (ws + 26247200);            // 1,200 B
    unsigned*  mode_flag = (unsigned*)(ws + 26248400);          // 4 B

    k_init_maps  <<<6400, 256, 0, stream>>>((uint4*)maps);
    k_select_sort<<<1, 1024, 0, stream>>>(cls, pboxes, cboxes, cscore, cfeat, clabel);
    k_nms        <<<NC, 64, 0, stream>>>(cboxes, clabel, keepflag);
    k_pick       <<<1, 64, 0, stream>>>(cscore, cfeat, keepflag, sel_score, sel_slot,
                                        qry2slot, refined, mode_flag);
    k_scatter    <<<3907, 256, 0, stream>>>(seg, xy, qry, refined, qry2slot, mode_flag, maps);
    k_output     <<<6400, 256, 0, stream>>>((const uint4*)maps, sel_score, sel_slot,
                                            (float4*)out);
}